// Round 11
// baseline (28.804 us; speedup 1.0000x reference)
//
#include <hip/hip_runtime.h>
#include <stdint.h>

typedef __attribute__((ext_vector_type(4)))  int i32x4;

// ws layout:
//   xm: uint4 [b=512][z=8][s=16]  (4 x u32 k-bitplanes)   1 MB
//   Bp: i8    [z=8][p=2][sl=8][j=128][k=128]              2 MB
#define XM_OFF 0u
#define BP_OFF 1048576u

__device__ __forceinline__ uint32_t q16(float v){
  float f = fminf(fmaxf(rintf(v*4096.f), -32768.f), 32767.f);
  return (uint32_t)(int)f & 0xffffu;
}

// ---------- fused pack: x -> bit-planes, w -> 2-bit slice planes, out <- quantized bias ----------
__global__ __launch_bounds__(256) void pack_k(const float* __restrict__ x, const float* __restrict__ w,
                                              const float* __restrict__ bias,
                                              uint4* __restrict__ xm, uint32_t* __restrict__ Bw,
                                              float* __restrict__ out){
  const int lane = threadIdx.x & 63;
  if (blockIdx.x < 1024){
    int wv = blockIdx.x*4 + (threadIdx.x >> 6);       // 0..4095
    int b = wv >> 3, z = wv & 7;
    const float* xp = x + b*1024 + z*128;
    uint32_t u0 = q16(xp[lane]);
    uint32_t u1 = q16(xp[lane + 64]);
    uint4 out4 = {0,0,0,0};
    #pragma unroll
    for (int s = 0; s < 16; ++s){
      unsigned long long m0 = __ballot((u0 >> s) & 1u);
      unsigned long long m1 = __ballot((u1 >> s) & 1u);
      if (lane == s){
        out4.x = (uint32_t)m0; out4.y = (uint32_t)(m0 >> 32);
        out4.z = (uint32_t)m1; out4.w = (uint32_t)(m1 >> 32);
      }
    }
    if (lane < 16) xm[(b*8 + z)*16 + lane] = out4;
  } else if (blockIdx.x < 1152){
    int t = (blockIdx.x - 1024)*256 + threadIdx.x;    // 32768
    int j = t >> 8, kq = t & 255;
    int r = kq >> 5, kd = kq & 31;
    float4 v = *reinterpret_cast<const float4*>(w + j*1024 + kq*4);
    #pragma unroll
    for (int p = 0; p < 2; ++p){
      uint32_t q0 = (uint32_t)fminf(rintf(fmaxf(p ? -v.x : v.x, 0.f)*4096.f), 65535.f);
      uint32_t q1 = (uint32_t)fminf(rintf(fmaxf(p ? -v.y : v.y, 0.f)*4096.f), 65535.f);
      uint32_t q2 = (uint32_t)fminf(rintf(fmaxf(p ? -v.z : v.z, 0.f)*4096.f), 65535.f);
      uint32_t q3 = (uint32_t)fminf(rintf(fmaxf(p ? -v.w : v.w, 0.f)*4096.f), 65535.f);
      #pragma unroll
      for (int sl = 0; sl < 8; ++sl){
        int sh = 2*(7 - sl);
        uint32_t word = ((q0 >> sh) & 3u) | (((q1 >> sh) & 3u) << 8)
                      | (((q2 >> sh) & 3u) << 16) | (((q3 >> sh) & 3u) << 24);
        Bw[(((r*2 + p)*8 + sl)*128 + j)*32 + kd] = word;
      }
    }
  } else {
    // out <- bias rounded to 2^-12 grid: all later atomic adds are exact & order-free
    int t = (blockIdx.x - 1152)*256 + threadIdx.x;    // 65536
    out[t] = rintf(bias[t & 127]*4096.f)*(1.0f/4096.0f);
  }
}

// ---------- main: 16x16x64 i8, 1 b x 16 j per wave, VGPR<=64 -> 8 waves/SIMD ----------
__global__ __launch_bounds__(512, 8) void mvm_main_k(const uint4* __restrict__ xm,
                                                     const uint8_t* __restrict__ Bp,
                                                     float* __restrict__ out){
  __shared__ uint8_t lds[16*2048];                    // 16 (p,sl) slots x 16j x 128k
  __shared__ uint32_t flg[16];
  const int tid = threadIdx.x, lane = tid & 63, wid = tid >> 6;
  const int bg = blockIdx.x, j16 = blockIdx.y, z = blockIdx.z;

  // ---- stage all 16 (p,sl) 16x128 slabs, XOR-swizzled; per-slot nonzero flags ----
  {
    const int si = tid >> 5;                          // slot 0..15 (2 per wave)
    const int u  = tid & 31;
    const int jj = u >> 1, h = u & 1;                 // row 0..15, 64B half
    const uint8_t* src = Bp + (((size_t)((z*16 + si)*128 + j16*16 + jj)) << 7) + h*64;
    uint4 v0 = *(const uint4*)(src);
    uint4 v1 = *(const uint4*)(src + 16);
    uint4 v2 = *(const uint4*)(src + 32);
    uint4 v3 = *(const uint4*)(src + 48);
    uint8_t* drow = lds + si*2048 + jj*128;
    const int m = jj & 7;
    *(uint4*)(drow + (size_t)(((h*4 + 0) ^ m) << 4)) = v0;
    *(uint4*)(drow + (size_t)(((h*4 + 1) ^ m) << 4)) = v1;
    *(uint4*)(drow + (size_t)(((h*4 + 2) ^ m) << 4)) = v2;
    *(uint4*)(drow + (size_t)(((h*4 + 3) ^ m) << 4)) = v3;
    uint32_t nz = v0.x|v0.y|v0.z|v0.w | v1.x|v1.y|v1.z|v1.w
                | v2.x|v2.y|v2.z|v2.w | v3.x|v3.y|v3.z|v3.w;
    unsigned long long bal = __ballot(nz != 0u);
    if (lane == 0){
      flg[wid*2]     = ((uint32_t)bal)         ? 1u : 0u;
      flg[wid*2 + 1] = ((uint32_t)(bal >> 32)) ? 1u : 0u;
    }
  }

  // ---- A fragments: 16 streams (rows) x K=128 bits of this wave's b ----
  const int b = bg*8 + wid;
  const int s = lane & 15, g = lane >> 4;             // row(stream)=s, k-group=g
  const uint4 pw = xm[(b*8 + z)*16 + s];
  uint32_t bits_a = (((g & 2) ? pw.y : pw.x) >> ((g & 1)*16)) & 0xFFFFu;   // k in [g*16, g*16+16)
  uint32_t bits_b = (((g & 2) ? pw.w : pw.z) >> ((g & 1)*16)) & 0xFFFFu;   // k in [64+g*16, ...)
  i32x4 A0, A1;
  #pragma unroll
  for (int r = 0; r < 4; ++r){
    A0[r] = (int)((((bits_a >> (r*4)) & 0xFu) * 0x204081u) & 0x01010101u);
    A1[r] = (int)((((bits_b >> (r*4)) & 0xFu) * 0x204081u) & 0x01010101u);
  }
  __syncthreads();

  uint32_t msk = 0;
  #pragma unroll
  for (int i = 0; i < 16; ++i) msk |= (flg[i] ? 1u : 0u) << i;
  msk = (uint32_t)__builtin_amdgcn_readfirstlane((int)msk);

  // swizzled B read offsets (lane-invariant over tiles): row j = s, chunks g and g+4
  const int jm = s & 7;
  const int o0 = s*128 + ((g    ) ^ jm)*16;
  const int o1 = s*128 + ((g + 4) ^ jm)*16;

  const i32x4 zz4 = {0, 0, 0, 0};
  const float C1 = (float)(511.0/384.0);
  const float QC = (float)(384.0/511.0/4096.0);
  const float w3 = (g == 3) ? -8.0f : 8.0f;           // stream 15 (two's-complement MSB) negative
  const float vf = (float)(1 << (4*g));               // 2^(4*g) stream-group scale

  float acc[2] = {0.f, 0.f};
  #pragma unroll
  for (int p = 0; p < 2; ++p){
    #pragma unroll
    for (int sl = 0; sl < 8; ++sl){
      const int ti = p*8 + sl;
      if (msk & (1u << ti)){
        const uint8_t* lb = lds + ti*2048;
        i32x4 B0 = *(const i32x4*)(lb + o0);
        i32x4 B1 = *(const i32x4*)(lb + o1);
        i32x4 cc = __builtin_amdgcn_mfma_i32_16x16x64_i8(A0, B0, zz4, 0, 0, 0);
        cc = __builtin_amdgcn_mfma_i32_16x16x64_i8(A1, B1, cc, 0, 0, 0);
        // ADC quantize 4 counts (rows s..s+3 of this lane-group) + stream/slice shift-add
        float nf0 = rintf((float)cc[0] * C1);
        float nf1 = rintf((float)cc[1] * C1);
        float nf2 = rintf((float)cc[2] * C1);
        float nf3 = rintf((float)cc[3] * C1);
        float t = fmaf(nf1, 2.f, nf0);
        t = fmaf(nf2, 4.f, t);
        t = fmaf(nf3, w3, t);
        const float slwvf = (float)(1 << (14 - 2*sl)) * vf;   // 4^(7-sl) * 2^(4g), exact pow2
        acc[p] = fmaf(t, slwvf, acc[p]);
      }
    }
  }

  // ---- reduce over the 4 lane-groups (streams), quantize per path, pos-neg, atomic ----
  float a0 = acc[0];
  a0 += __shfl_xor(a0, 16); a0 += __shfl_xor(a0, 32);
  float a1 = acc[1];
  a1 += __shfl_xor(a1, 16); a1 += __shfl_xor(a1, 32);
  float q0 = fminf(fmaxf(rintf(a0*QC)*(1.0f/4096.0f), -8.0f), 8.0f - 1.0f/4096.0f);
  float q1 = fminf(fmaxf(rintf(a1*QC)*(1.0f/4096.0f), -8.0f), 8.0f - 1.0f/4096.0f);
  // exact float atomics: addends multiples of 2^-12, totals < 2^8 -> order-independent
  if (lane < 16) atomicAdd(&out[b*128 + j16*16 + lane], q0 - q1);
}

extern "C" void kernel_launch(void* const* d_in, const int* in_sizes, int n_in,
                              void* d_out, int out_size, void* d_ws, size_t ws_size,
                              hipStream_t stream){
  const float* x    = (const float*)d_in[0];
  const float* w    = (const float*)d_in[1];
  const float* bias = (const float*)d_in[2];
  uint8_t* ws = (uint8_t*)d_ws;
  float* out = (float*)d_out;

  hipLaunchKernelGGL(pack_k, dim3(1408), dim3(256), 0, stream,
                     x, w, bias, (uint4*)(ws + XM_OFF), (uint32_t*)(ws + BP_OFF), out);
  hipLaunchKernelGGL(mvm_main_k, dim3(64, 8, 8), dim3(512), 0, stream,
                     (const uint4*)(ws + XM_OFF), ws + BP_OFF, out);
}

// Round 12
// 25.363 us; speedup vs baseline: 1.1357x; 1.1357x over previous
//
#include <hip/hip_runtime.h>
#include <stdint.h>

typedef __attribute__((ext_vector_type(4)))  int i32x4;
typedef __attribute__((ext_vector_type(16))) int i32x16;

// ws layout:
//   xm: uint4 [b=512][z=8][s=16]  (4 x u32 k-bitplanes)   1 MB
//   Bp: i8    [z=8][p=2][sl=8][j=128][k=128]              2 MB
//   mk: u16   [z=8][j=128]  per-(z,j) live-tile mask      2 KB
#define XM_OFF 0u
#define BP_OFF 1048576u
#define MK_OFF 3145728u

__device__ __forceinline__ uint32_t q16(float v){
  float f = fminf(fmaxf(rintf(v*4096.f), -32768.f), 32767.f);
  return (uint32_t)(int)f & 0xffffu;
}

// ---------- fused pack: x -> bit-planes, w -> slice planes + per-j masks, out <- bias ----------
__global__ __launch_bounds__(256) void pack_k(const float* __restrict__ x, const float* __restrict__ w,
                                              const float* __restrict__ bias,
                                              uint4* __restrict__ xm, uint32_t* __restrict__ Bw,
                                              uint16_t* __restrict__ mk, float* __restrict__ out){
  const int lane = threadIdx.x & 63;
  if (blockIdx.x < 1024){
    int wv = blockIdx.x*4 + (threadIdx.x >> 6);       // 0..4095
    int b = wv >> 3, z = wv & 7;
    const float* xp = x + b*1024 + z*128;
    uint32_t u0 = q16(xp[lane]);
    uint32_t u1 = q16(xp[lane + 64]);
    uint4 out4 = {0,0,0,0};
    #pragma unroll
    for (int s = 0; s < 16; ++s){
      unsigned long long m0 = __ballot((u0 >> s) & 1u);
      unsigned long long m1 = __ballot((u1 >> s) & 1u);
      if (lane == s){
        out4.x = (uint32_t)m0; out4.y = (uint32_t)(m0 >> 32);
        out4.z = (uint32_t)m1; out4.w = (uint32_t)(m1 >> 32);
      }
    }
    if (lane < 16) xm[(b*8 + z)*16 + lane] = out4;
  } else if (blockIdx.x < 1152){
    int t = (blockIdx.x - 1024)*256 + threadIdx.x;    // 32768; one j per block
    int j = t >> 8, kq = t & 255;
    int r = kq >> 5, kd = kq & 31;                    // each 32-lane half: one r
    float4 v = *reinterpret_cast<const float4*>(w + j*1024 + kq*4);
    uint32_t lm = 0;
    #pragma unroll
    for (int p = 0; p < 2; ++p){
      uint32_t q0 = (uint32_t)fminf(rintf(fmaxf(p ? -v.x : v.x, 0.f)*4096.f), 65535.f);
      uint32_t q1 = (uint32_t)fminf(rintf(fmaxf(p ? -v.y : v.y, 0.f)*4096.f), 65535.f);
      uint32_t q2 = (uint32_t)fminf(rintf(fmaxf(p ? -v.z : v.z, 0.f)*4096.f), 65535.f);
      uint32_t q3 = (uint32_t)fminf(rintf(fmaxf(p ? -v.w : v.w, 0.f)*4096.f), 65535.f);
      #pragma unroll
      for (int sl = 0; sl < 8; ++sl){
        int sh = 2*(7 - sl);
        uint32_t word = ((q0 >> sh) & 3u) | (((q1 >> sh) & 3u) << 8)
                      | (((q2 >> sh) & 3u) << 16) | (((q3 >> sh) & 3u) << 24);
        Bw[(((r*2 + p)*8 + sl)*128 + j)*32 + kd] = word;
        lm |= (word != 0u ? 1u : 0u) << (p*8 + sl);
      }
    }
    lm |= (uint32_t)__shfl_xor((int)lm, 16);
    lm |= (uint32_t)__shfl_xor((int)lm, 8);
    lm |= (uint32_t)__shfl_xor((int)lm, 4);
    lm |= (uint32_t)__shfl_xor((int)lm, 2);
    lm |= (uint32_t)__shfl_xor((int)lm, 1);
    if ((threadIdx.x & 31) == 0) mk[r*128 + j] = (uint16_t)lm;  // one writer per (z,j): race-free
  } else {
    // out <- bias rounded to 2^-12 grid: all later atomic adds are exact & order-free
    int t = (blockIdx.x - 1152)*256 + threadIdx.x;    // 65536
    out[t] = rintf(bias[t & 127]*4096.f)*(1.0f/4096.0f);
  }
}

// ---------- main: 32x32x32, single A-frag/wave, compact 13-slot staging -> 6 waves/SIMD ----------
__global__ __launch_bounds__(512, 6) void mvm_main_k(const uint4* __restrict__ xm,
                                                     const uint8_t* __restrict__ Bp,
                                                     const uint16_t* __restrict__ mk,
                                                     float* __restrict__ out){
  __shared__ uint8_t lds[13*4096];                    // 52 KB -> 3 blocks/CU
  const int tid = threadIdx.x, lane = tid & 63, wid = tid >> 6;
  const int z = blockIdx.z, jblk = blockIdx.y;
  const int col = lane & 31, hi = lane >> 5;

  // ---- wave-uniform live mask: OR of 32 per-j masks (16 u32 loads + shfl reduce) ----
  uint32_t mv = ((const uint32_t*)mk)[z*64 + jblk*16 + (lane & 15)];
  mv |= (uint32_t)__shfl_xor((int)mv, 1);
  mv |= (uint32_t)__shfl_xor((int)mv, 2);
  mv |= (uint32_t)__shfl_xor((int)mv, 4);
  mv |= (uint32_t)__shfl_xor((int)mv, 8);
  const uint32_t msk = (uint32_t)__builtin_amdgcn_readfirstlane((int)((mv | (mv >> 16)) & 0xFFFFu));

  // ---- compact staging: live tiles -> slots 0..12 (swizzled); slot>=13 read from L2 later ----
  {
    const int q = lane >> 3, cS = (lane & 7) ^ q;
    int slot = 0;
    #pragma unroll
    for (int ti = 0; ti < 16; ++ti){
      if (msk & (1u << ti)){
        if ((slot == wid || slot == wid + 8) && slot < 13){
          const uint8_t* src = Bp + ((size_t)((z*16 + ti)*128 + jblk*32) << 7);
          uint4 r0 = *(const uint4*)(src + (q     )*128 + cS*16);
          uint4 r1 = *(const uint4*)(src + (q +  8)*128 + cS*16);
          uint4 r2 = *(const uint4*)(src + (q + 16)*128 + cS*16);
          uint4 r3 = *(const uint4*)(src + (q + 24)*128 + cS*16);
          uint8_t* dst = lds + slot*4096 + lane*16;
          *(uint4*)(dst       ) = r0;
          *(uint4*)(dst + 1024) = r1;
          *(uint4*)(dst + 2048) = r2;
          *(uint4*)(dst + 3072) = r3;
        }
        ++slot;
      }
    }
  }

  // ---- A fragments: ONE b-pair per wave (M=32 = 2b x 16s), verified mapping ----
  const int bb  = blockIdx.x*16 + wid*2;
  const int s_a = lane & 15;
  const uint4 pw = xm[((bb + (col >> 4))*8 + z)*16 + s_a];
  i32x4 afr[4];
  {
    const uint32_t wd[4] = {pw.x, pw.y, pw.z, pw.w};
    #pragma unroll
    for (int f = 0; f < 4; ++f){
      uint32_t pl = wd[f] >> (hi*16);
      #pragma unroll
      for (int wI = 0; wI < 4; ++wI)
        afr[f][wI] = (int)((((pl >> (wI*4)) & 0xFu) * 0x204081u) & 0x01010101u);
    }
  }
  __syncthreads();

  const int c7 = col & 7;
  const int xo0 = ((0 + hi) ^ c7) << 4;
  const int xo1 = ((2 + hi) ^ c7) << 4;
  const int xo2 = ((4 + hi) ^ c7) << 4;
  const int xo3 = ((6 + hi) ^ c7) << 4;

  i32x16 zz;
  #pragma unroll
  for (int i = 0; i < 16; ++i) zz[i] = 0;

  const float C1 = (float)(511.0/384.0);
  const float QC = (float)(384.0/511.0/4096.0);
  const float sc = hi ? 16.0f : 1.0f;                 // 2^(4*hi)
  const float w7 = hi ? -8.0f : 8.0f;                 // stream 15 (s_lo=11, hi=1) negative
  float a00 = 0.f, a01 = 0.f, a10 = 0.f, a11 = 0.f;  // a{p}{row-half}

#define EPI(cc, A0, A1) do { \
    float nf[16]; \
    _Pragma("unroll") \
    for (int g_ = 0; g_ < 16; ++g_) nf[g_] = rintf((float)cc[g_] * C1); \
    float t0 = fmaf(nf[1], 2.f, nf[0]);  t0 = fmaf(nf[2], 4.f, t0);  t0 = fmaf(nf[3], 8.f, t0); \
    float t1 = fmaf(nf[5], 2.f, nf[4]);  t1 = fmaf(nf[6], 4.f, t1);  t1 = fmaf(nf[7], w7, t1); \
    float t2 = fmaf(nf[9], 2.f, nf[8]);  t2 = fmaf(nf[10],4.f, t2);  t2 = fmaf(nf[11],8.f, t2); \
    float t3 = fmaf(nf[13],2.f, nf[12]); t3 = fmaf(nf[14],4.f, t3);  t3 = fmaf(nf[15],w7, t3); \
    A0 = fmaf(t0, slwv, A0);  A0 = fmaf(t1, slw256, A0); \
    A1 = fmaf(t2, slwv, A1);  A1 = fmaf(t3, slw256, A1); \
  } while (0)

  {
    int slot2 = 0;
    #pragma unroll
    for (int ti = 0; ti < 16; ++ti){
      if (msk & (1u << ti)){
        const int sl = ti & 7;
        const float slwv   = (float)(1 << (14 - 2*sl));  // 4^(7-sl)
        const float slw256 = slwv * 256.0f;
        i32x4 b0, b1, b2, b3;
        if (slot2 < 13){
          const uint8_t* lb = lds + slot2*4096 + col*128;
          b0 = *(const i32x4*)(lb + xo0);
          b1 = *(const i32x4*)(lb + xo1);
          b2 = *(const i32x4*)(lb + xo2);
          b3 = *(const i32x4*)(lb + xo3);
        } else {
          // overflow fallback (>13 live tiles): direct L2 read, unswizzled chunks (2f+hi)
          const uint8_t* gb = Bp + ((size_t)((z*16 + ti)*128 + jblk*32 + col) << 7) + hi*16;
          b0 = *(const i32x4*)(gb      );
          b1 = *(const i32x4*)(gb + 32 );
          b2 = *(const i32x4*)(gb + 64 );
          b3 = *(const i32x4*)(gb + 96 );
        }
        i32x16 cc = __builtin_amdgcn_mfma_i32_32x32x32_i8(afr[0], b0, zz, 0, 0, 0);
        cc = __builtin_amdgcn_mfma_i32_32x32x32_i8(afr[1], b1, cc, 0, 0, 0);
        cc = __builtin_amdgcn_mfma_i32_32x32x32_i8(afr[2], b2, cc, 0, 0, 0);
        cc = __builtin_amdgcn_mfma_i32_32x32x32_i8(afr[3], b3, cc, 0, 0, 0);
        if (ti < 8) EPI(cc, a00, a01);
        else        EPI(cc, a10, a11);
        ++slot2;
      }
    }
  }
#undef EPI

  // ---- per-path accumulator quantization, pos - neg, exact atomic ----
  a00 *= sc; a01 *= sc; a10 *= sc; a11 *= sc;
  a00 += __shfl_xor(a00, 32); a01 += __shfl_xor(a01, 32);
  a10 += __shfl_xor(a10, 32); a11 += __shfl_xor(a11, 32);
  float q00 = fminf(fmaxf(rintf(a00*QC)*(1.0f/4096.0f), -8.0f), 8.0f - 1.0f/4096.0f);
  float q01 = fminf(fmaxf(rintf(a01*QC)*(1.0f/4096.0f), -8.0f), 8.0f - 1.0f/4096.0f);
  float q10 = fminf(fmaxf(rintf(a10*QC)*(1.0f/4096.0f), -8.0f), 8.0f - 1.0f/4096.0f);
  float q11 = fminf(fmaxf(rintf(a11*QC)*(1.0f/4096.0f), -8.0f), 8.0f - 1.0f/4096.0f);
  const float o0 = q00 - q10;                         // b = bb
  const float o1 = q01 - q11;                         // b = bb+1
  // exact float atomics: addends multiples of 2^-12, totals < 2^8 -> order-independent
  const int jout = jblk*32 + col;
  atomicAdd(&out[(bb + hi)*128 + jout], hi ? o1 : o0);
}

extern "C" void kernel_launch(void* const* d_in, const int* in_sizes, int n_in,
                              void* d_out, int out_size, void* d_ws, size_t ws_size,
                              hipStream_t stream){
  const float* x    = (const float*)d_in[0];
  const float* w    = (const float*)d_in[1];
  const float* bias = (const float*)d_in[2];
  uint8_t* ws = (uint8_t*)d_ws;
  float* out = (float*)d_out;

  hipLaunchKernelGGL(pack_k, dim3(1408), dim3(256), 0, stream,
                     x, w, bias, (uint4*)(ws + XM_OFF), (uint32_t*)(ws + BP_OFF),
                     (uint16_t*)(ws + MK_OFF), out);
  hipLaunchKernelGGL(mvm_main_k, dim3(32, 4, 8), dim3(512), 0, stream,
                     (const uint4*)(ws + XM_OFF), ws + BP_OFF,
                     (const uint16_t*)(ws + MK_OFF), out);
}